// Round 5
// baseline (997.834 us; speedup 1.0000x reference)
//
#include <hip/hip_runtime.h>

#define H    51
#define BB   2048
#define TSEQ 1024
#define NB   8
#define NT   1024       // 16 waves, 4/SIMD
#define KP   72         // bf16 h-row stride (144B, 16B-aligned)

typedef __attribute__((ext_vector_type(8))) short short8;
typedef __attribute__((ext_vector_type(4))) float f32x4;

// v_rcp_f32 (1 ulp) via compiler-known intrinsic (proven r3)
__device__ __forceinline__ float rcp_(float x) { return __builtin_amdgcn_rcpf(x); }

__device__ __forceinline__ float sigm(float x) { return rcp_(1.0f + __expf(-x)); }
__device__ __forceinline__ float tanh_(float x) { return fmaf(-2.0f, rcp_(__expf(2.0f * x) + 1.0f), 1.0f); }

__device__ __forceinline__ unsigned short f2bf(float f) {
    unsigned u = __float_as_uint(f);
    return (unsigned short)((u + 0x7fffu + ((u >> 16) & 1u)) >> 16);   // RNE
}
__device__ __forceinline__ float bf2f(unsigned short s) { return __uint_as_float(((unsigned)s) << 16); }

// pack two RNE bf16 into one dword: lo=cvt(a), hi=cvt(b)
__device__ __forceinline__ unsigned pk2bf(float a, float b) {
    unsigned r;
    asm("v_cvt_pk_bf16_f32 %0, %1, %2" : "=v"(r) : "v"(a), "v"(b));
    return r;
}

#define MFMA(a, b, c) __builtin_amdgcn_mfma_f32_16x16x32_bf16((a), (b), (c), 0, 0, 0)

// lgkmcnt-only barrier (proven r3): LDS ordering without draining vmcnt.
#define BARR() do { asm volatile("s_waitcnt lgkmcnt(0)" ::: "memory");            \
                    __builtin_amdgcn_s_barrier(); } while (0)

struct SM {
    alignas(16) short h1[2][8][KP];       // parity-buffered h1 (bf16); 8 real batch rows
    alignas(16) short h2[2][8][KP];       // lanes n>=8 re-read row n-8 (broadcast)
    alignas(16) float part[2][16][4][8];  // out partials [parity][tile(pad16)][q][batch]
    alignas(16) float xstep[2][8][4];     // parity-chunked x staging [buf][batch][slot]
    float olds[8];
};

// A-frags (hi/lo split) for tile T of gate-stacked [3H][H] matrix, 4-padded rows:
// padded row 16T+n -> element j=4T+(n>>2), gate slot c=n&3.
// nslot selects which slot carries the n-gate row (2 = normal; 3 = moved).
__device__ __forceinline__ void loadA(const float* __restrict__ src, int T, int n, int q,
                                      short8* ah, short8* al, int nslot) {
    const int jt = 4 * T + (n >> 2);
    const int c  = n & 3;
    const int g  = (c == 0) ? 0 : (c == 1) ? 1 : (c == nslot) ? 2 : -1;
    const bool rv = (g >= 0) && (jt < H);
#pragma unroll
    for (int kb = 0; kb < 2; ++kb) {
        short8 hi, lo;
#pragma unroll
        for (int jj = 0; jj < 8; ++jj) {
            const int k = kb * 32 + q * 8 + jj;
            const float v = (rv && k < H) ? src[(g * H + jt) * H + k] : 0.f;
            const unsigned short hb = f2bf(v);
            hi[jj] = (short)hb;
            lo[jj] = (short)f2bf(v - bf2f(hb));
        }
        ah[kb] = hi; al[kb] = lo;
    }
}

// chained 4-MFMA 2-term split matvec, bias/partial folded into accumulator init
__device__ __forceinline__ f32x4 dot4(const short8* ah, const short8* al,
                                      short8 b0, short8 b1, f32x4 init) {
    f32x4 acc = init;
    acc = MFMA(al[0], b0, acc);
    acc = MFMA(al[1], b1, acc);
    acc = MFMA(ah[0], b0, acc);
    acc = MFMA(ah[1], b1, acc);
    return acc;
}

__global__ __launch_bounds__(NT, 1) void gru_persist(
    const float* __restrict__ inp, const int* __restrict__ fut,
    const float* __restrict__ wih1, const float* __restrict__ whh1,
    const float* __restrict__ bih1, const float* __restrict__ bhh1,
    const float* __restrict__ wih2, const float* __restrict__ whh2,
    const float* __restrict__ bih2, const float* __restrict__ bhh2,
    const float* __restrict__ wlin, const float* __restrict__ blin,
    float* __restrict__ out)
{
    __shared__ SM sm;
    const int t = threadIdx.x, bg = blockIdx.x;
    const int w = t >> 6, lane = t & 63;
    const int n = lane & 15, q = lane >> 4;
    // SIMD balance (proven r4): tile 12 on wave 15 -> light waves {12,13,14,15}
    // land on distinct SIMDs; every SIMD carries 3 matvec + 1 light wave.
    const bool doM = (w < 12) || (w == 15);
    const int  T   = (w == 15) ? 12 : (doM ? w : 0);
    const int  j   = 4 * T + q;
    const bool jv  = doM && (j < H) && (n < NB);
    // paired-write ownership: q-even lanes of real batches write dword (j, j+1)
    const bool wv  = doM && (n < NB) && ((q & 1) == 0);
    const int  jcl = (j < H) ? j : 0;

    // ---- A-fragments: 12 short8 = 48 VGPRs (wih2's n-row in slot 3) ----
    short8 a1h[2], a1l[2], a2h[2], a2l[2], a3h[2], a3l[2];
    loadA(whh1, T, n, q, a1h, a1l, 2);
    loadA(whh2, T, n, q, a2h, a2l, 2);
    loadA(wih2, T, n, q, a3h, a3l, 3);

    // ---- per-lane constants; biases folded into f32x4 accumulator inits ----
    // L1 chain: .x/.y = both r/z biases, .z = bhh1n, .w = bih1n (zero slot-3 row)
    const f32x4 b1v  = {bhh1[jcl] + bih1[jcl], bhh1[H + jcl] + bih1[H + jcl],
                        bhh1[2 * H + jcl], bih1[2 * H + jcl]};
    // L2 split inits: two independent 4-MFMA chains (halves dependent depth)
    const f32x4 ib2v = {bhh2[jcl], bhh2[H + jcl], bhh2[2 * H + jcl], 0.f};
    const f32x4 ic2v = {bih2[jcl], bih2[H + jcl], 0.f, bih2[2 * H + jcl]};
    const float w1r = wih1[jcl], w1z = wih1[H + jcl], w1n = wih1[2 * H + jcl];
    const float wl  = wlin[jcl];
    const float blin_r = blin[0];

    // ---- LDS init ----
    for (int i = t; i < 2 * 8 * KP; i += NT) { ((short*)sm.h1)[i] = 0; ((short*)sm.h2)[i] = 0; }
    for (int i = t; i < 2 * 16 * 4 * 8; i += NT) ((float*)sm.part)[i] = 0.f;
    if (t < 8) sm.olds[t] = 0.f;

    // ---- x staging: wave 13, lanes 0..7; parity-chunked double buffer ----
    const bool doX = (w == 13) && (lane < 8);
    const int  bs  = lane;
    const float* xrow = inp + (size_t)(bg * NB + (doX ? bs : 0)) * TSEQ;
    float4 xnxt = make_float4(0.f, 0.f, 0.f, 0.f);
    if (doX) {
        *(float4*)&sm.xstep[0][bs][0] = *(const float4*)xrow;     // x[0..3]
        xnxt = *(const float4*)(xrow + 4);                        // x[4..7]
    }

    float h1o = 0.f, h2o = 0.f;     // per-lane f32 hidden (element j, batch n)
    const int TT = TSEQ + fut[0];
    float* outp = out + (size_t)(bg * NB) * (size_t)TT;
    __syncthreads();

// paired bf16 dword h-write: partner via lane-xor-16 (q<->q^1), pack, q-even write.
// 16 writer lanes hit 16 distinct banks -> conflict-free; bits identical to the
// old per-lane 2-byte RNE stores. (Tile 12 q=3 writes j=51 pad: A is zero for
// k>=51, and hn is bounded by the convex GRU update -> harmless.)
#define HWRITE(ARR, PARI, HNV)                                                    \
{                                                                                 \
    const float hp_ = __shfl_xor((HNV), 16);                                      \
    if (wv) *(unsigned*)&sm.ARR[PARI][n][4 * T + q] = pk2bf((HNV), hp_);          \
}

// wave-14 full output reduction: 13x4 tile-q partials per batch; conflict-free
#define RED14(PBUF, TIDX, SAVEO)                                                  \
{                                                                                 \
    const float* pb = &sm.part[PBUF][0][0][0];                                    \
    float v = 0.f;                                                                \
    _Pragma("unroll")                                                             \
    for (int c = 0; c < 8; ++c) v += pb[64 * c + lane];                           \
    v += __shfl_xor(v, 8);                                                        \
    v += __shfl_xor(v, 16);                                                       \
    v += __shfl_xor(v, 32);                                                       \
    if (lane < 8) {                                                               \
        const float o_ = v + blin_r;                                              \
        if (SAVEO) sm.olds[lane] = o_;                                            \
        outp[(size_t)lane * TT + (TIDX)] = o_;                                    \
    }                                                                             \
}

#define STEP(IV, PAR, DOL2, DORED)                                                \
{                                                                                 \
    const int i_ = (IV);                                                          \
    if (doM) {                                                                    \
        const short8 b10 = *(const short8*)&sm.h1[PAR][n & 7][q * 8];             \
        const short8 b11 = *(const short8*)&sm.h1[PAR][n & 7][32 + q * 8];        \
        if (DOL2) {                                                               \
            const short8 b20 = *(const short8*)&sm.h2[PAR][n & 7][q * 8];         \
            const short8 b21 = *(const short8*)&sm.h2[PAR][n & 7][32 + q * 8];    \
            const f32x4 g  = dot4(a2h, a2l, b20, b21, ib2v);                      \
            const f32x4 gi = dot4(a3h, a3l, b10, b11, ic2v);                      \
            const float gr = sigm(g.x + gi.x);                                    \
            const float gz = sigm(g.y + gi.y);                                    \
            const float gn = tanh_(fmaf(gr, g.z, gi.w));                          \
            const float hn = gn + gz * (h2o - gn);                                \
            h2o = hn;                                                             \
            HWRITE(h2, (PAR) ^ 1, hn)                                             \
            if (jv) sm.part[PAR][T][q][n] = wl * hn;                              \
        }                                                                         \
        {                                                                         \
            const float xv = sm.xstep[(i_ >> 2) & 1][n & 7][i_ & 3];              \
            const f32x4 a = dot4(a1h, a1l, b10, b11, b1v);                        \
            const float gr = sigm(fmaf(xv, w1r, a.x));                            \
            const float gz = sigm(fmaf(xv, w1z, a.y));                            \
            const float gn = tanh_(fmaf(gr, a.z, fmaf(xv, w1n, a.w)));            \
            const float hn = gn + gz * (h1o - gn);                                \
            h1o = hn;                                                             \
            HWRITE(h1, (PAR) ^ 1, hn)                                             \
        }                                                                         \
    } else if (w == 14) {                                                         \
        if (DORED) RED14((PAR) ^ 1, i_ - 2, false)                                \
    } else if (doX && (i_ & 3) == 3 && (i_ + 1) < TSEQ) {                         \
        *(float4*)&sm.xstep[((i_ + 1) >> 2) & 1][bs][0] = xnxt;                   \
        if (i_ + 8 < TSEQ) xnxt = *(const float4*)(xrow + i_ + 5);                \
    }                                                                             \
    BARR();                                                                       \
}

    // ========== MAIN LOOP: 1 barrier/step, parity-specialized unroll-2 ==========
    STEP(0, 0, false, false)
    STEP(1, 1, true,  false)
    for (int i = 2; i < TSEQ; i += 2) {
        STEP(i,     0, true, true)
        STEP(i + 1, 1, true, true)
    }

    // ========== EPILOGUE: h2(TSEQ-1), flush o(TSEQ-2) and o(TSEQ-1) ==========
    // state: h1(TSEQ-1) in h1[0], h2(TSEQ-2) in h2[0]; part[1] holds o(TSEQ-2) partials
    if (doM) {
        const short8 b10 = *(const short8*)&sm.h1[0][n & 7][q * 8];
        const short8 b11 = *(const short8*)&sm.h1[0][n & 7][32 + q * 8];
        const short8 b20 = *(const short8*)&sm.h2[0][n & 7][q * 8];
        const short8 b21 = *(const short8*)&sm.h2[0][n & 7][32 + q * 8];
        const f32x4 g  = dot4(a2h, a2l, b20, b21, ib2v);
        const f32x4 gi = dot4(a3h, a3l, b10, b11, ic2v);
        const float gr = sigm(g.x + gi.x);
        const float gz = sigm(g.y + gi.y);
        const float gn = tanh_(fmaf(gr, g.z, gi.w));
        const float hn = gn + gz * (h2o - gn);
        h2o = hn;
        HWRITE(h2, 1, hn)
        if (jv) sm.part[0][T][q][n] = wl * hn;
    } else if (w == 14) {
        RED14(1, TSEQ - 2, false)
    }
    BARR();
    if (w == 14) {
        RED14(0, TSEQ - 1, true)
    }
    BARR();

    // ========== FUTURE LOOP: serial feedback, 3 barriers/step ==========
    int fp1 = 0, fh2 = 1;    // h1(TSEQ-1) in h1[0], h2(TSEQ-1) in h2[1]
    for (int ts = TSEQ; ts < TT; ++ts) {
        float g2r, g2z, g2n;
        if (doM) {
            const short8 b10 = *(const short8*)&sm.h1[fp1][n & 7][q * 8];
            const short8 b11 = *(const short8*)&sm.h1[fp1][n & 7][32 + q * 8];
            const short8 b20 = *(const short8*)&sm.h2[fh2][n & 7][q * 8];
            const short8 b21 = *(const short8*)&sm.h2[fh2][n & 7][32 + q * 8];
            const float  xv  = sm.olds[n & 7];
            {
                const f32x4 g = dot4(a2h, a2l, b20, b21, ib2v);
                g2r = g.x; g2z = g.y; g2n = g.z;
            }
            {
                const f32x4 a = dot4(a1h, a1l, b10, b11, b1v);
                const float gr = sigm(fmaf(xv, w1r, a.x));
                const float gz = sigm(fmaf(xv, w1z, a.y));
                const float gn = tanh_(fmaf(gr, a.z, fmaf(xv, w1n, a.w)));
                const float hn = gn + gz * (h1o - gn);
                h1o = hn;
                HWRITE(h1, fp1 ^ 1, hn)
            }
        }
        BARR();
        if (doM) {
            const short8 c0 = *(const short8*)&sm.h1[fp1 ^ 1][n & 7][q * 8];
            const short8 c1 = *(const short8*)&sm.h1[fp1 ^ 1][n & 7][32 + q * 8];
            const f32x4 gi = dot4(a3h, a3l, c0, c1, ic2v);   // n-part lands in .w
            const float gr = sigm(gi.x + g2r);
            const float gz = sigm(gi.y + g2z);
            const float gn = tanh_(fmaf(gr, g2n, gi.w));
            const float hn = gn + gz * (h2o - gn);
            h2o = hn;
            HWRITE(h2, fh2 ^ 1, hn)
            if (jv) sm.part[0][T][q][n] = wl * hn;
        }
        BARR();
        if (w == 14) {
            RED14(0, ts, true)
        }
        BARR();
        fp1 ^= 1; fh2 ^= 1;
    }
}

extern "C" void kernel_launch(void* const* d_in, const int* in_sizes, int n_in,
                              void* d_out, int out_size, void* d_ws, size_t ws_size,
                              hipStream_t stream) {
    (void)in_sizes; (void)n_in; (void)d_ws; (void)ws_size; (void)out_size;
    gru_persist<<<BB / NB, NT, 0, stream>>>(
        (const float*)d_in[0], (const int*)d_in[1],
        (const float*)d_in[2], (const float*)d_in[3], (const float*)d_in[4], (const float*)d_in[5],
        (const float*)d_in[6], (const float*)d_in[7], (const float*)d_in[8], (const float*)d_in[9],
        (const float*)d_in[10], (const float*)d_in[11],
        (float*)d_out);
}

// Round 6
// 930.403 us; speedup vs baseline: 1.0725x; 1.0725x over previous
//
#include <hip/hip_runtime.h>

#define H    51
#define BB   2048
#define TSEQ 1024
#define NB   8
#define NT   512        // 8 waves, 2/SIMD
#define KP   72         // bf16 h-row stride (144B, 16B-aligned)

typedef __attribute__((ext_vector_type(8))) short short8;
typedef __attribute__((ext_vector_type(4))) float f32x4;

// v_rcp_f32 (1 ulp) via compiler-known intrinsic (proven r3)
__device__ __forceinline__ float rcp_(float x) { return __builtin_amdgcn_rcpf(x); }

__device__ __forceinline__ float sigm(float x) { return rcp_(1.0f + __expf(-x)); }
__device__ __forceinline__ float tanh_(float x) { return fmaf(-2.0f, rcp_(__expf(2.0f * x) + 1.0f), 1.0f); }

__device__ __forceinline__ unsigned short f2bf(float f) {
    unsigned u = __float_as_uint(f);
    return (unsigned short)((u + 0x7fffu + ((u >> 16) & 1u)) >> 16);   // RNE
}
__device__ __forceinline__ float bf2f(unsigned short s) { return __uint_as_float(((unsigned)s) << 16); }

// single-instruction RNE f32->bf16 (low half of v_cvt_pk_bf16_f32); proven r1/r3/r4
__device__ __forceinline__ short f2bf_rn(float f) {
    unsigned r;
    asm("v_cvt_pk_bf16_f32 %0, %1, %2" : "=v"(r) : "v"(f), "v"(f));
    return (short)r;
}

#define MFMA(a, b, c) __builtin_amdgcn_mfma_f32_16x16x32_bf16((a), (b), (c), 0, 0, 0)

// lgkmcnt-only barrier (proven r3/r4): LDS ordering without draining vmcnt.
#define BARR() do { asm volatile("s_waitcnt lgkmcnt(0)" ::: "memory");            \
                    __builtin_amdgcn_s_barrier(); } while (0)

struct SM {
    alignas(16) short h1[2][16][KP];      // parity-buffered h1 (bf16); rows 8-15 stay zero
    alignas(16) short h2[2][16][KP];
    alignas(16) float part[2][16][4][8];  // out partials [parity][tile(pad16)][q][batch]
    alignas(16) float xstep[2][8][4];     // parity-chunked x staging [buf][batch][slot]
    float olds[8];
};

// A-frags (hi/lo split) for tile T of gate-stacked [3H][H] matrix, 4-padded rows:
// padded row 16T+n -> element j=4T+(n>>2), gate slot c=n&3.
// nslot selects which slot carries the n-gate row (2 = normal; 3 = moved).
__device__ __forceinline__ void loadA(const float* __restrict__ src, int T, int n, int q,
                                      short8* ah, short8* al, int nslot) {
    const int jt = 4 * T + (n >> 2);
    const int c  = n & 3;
    const int g  = (c == 0) ? 0 : (c == 1) ? 1 : (c == nslot) ? 2 : -1;
    const bool rv = (g >= 0) && (jt < H);
#pragma unroll
    for (int kb = 0; kb < 2; ++kb) {
        short8 hi, lo;
#pragma unroll
        for (int jj = 0; jj < 8; ++jj) {
            const int k = kb * 32 + q * 8 + jj;
            const float v = (rv && k < H) ? src[(g * H + jt) * H + k] : 0.f;
            const unsigned short hb = f2bf(v);
            hi[jj] = (short)hb;
            lo[jj] = (short)f2bf(v - bf2f(hb));
        }
        ah[kb] = hi; al[kb] = lo;
    }
}

// chained 4-MFMA 2-term split matvec, bias/partial folded into accumulator init
__device__ __forceinline__ f32x4 dot4(const short8* ah, const short8* al,
                                      short8 b0, short8 b1, f32x4 init) {
    f32x4 acc = init;
    acc = MFMA(al[0], b0, acc);
    acc = MFMA(al[1], b1, acc);
    acc = MFMA(ah[0], b0, acc);
    acc = MFMA(ah[1], b1, acc);
    return acc;
}

__global__ __launch_bounds__(NT, 1) void gru_persist(
    const float* __restrict__ inp, const int* __restrict__ fut,
    const float* __restrict__ wih1, const float* __restrict__ whh1,
    const float* __restrict__ bih1, const float* __restrict__ bhh1,
    const float* __restrict__ wih2, const float* __restrict__ whh2,
    const float* __restrict__ bih2, const float* __restrict__ bhh2,
    const float* __restrict__ wlin, const float* __restrict__ blin,
    float* __restrict__ out)
{
    __shared__ SM sm;
    const int t = threadIdx.x, bg = blockIdx.x;
    const int w = t >> 6, lane = t & 63;
    const int n = lane & 15, q = lane >> 4;

    // Fat-wave tiling: every wave is a matvec wave; one SHARED set of b-fragment
    // ds_reads serves all of a wave's tiles (LDS read traffic 52 -> 32 b128/step).
    // w0..w4: tiles (2w, 2w+1); w5: T10; w6: T11 (+x-staging); w7: T12 (+reduction).
    // Round-robin w%4 SIMD placement -> per-SIMD tiles (4,3,3,3) - pigeonhole optimal.
    const bool twoT = (w < 5);
    const int  Ta   = twoT ? 2 * w : (w + 5);
    const int  Tb   = twoT ? 2 * w + 1 : 13;      // 13 = virtual (never computed)

    // ---- per-tile state: A-frags, folded biases, hidden regs ----
#define DECL_TILE(SFX, TVAL)                                                      \
    const int  T##SFX  = (TVAL);                                                  \
    const int  j##SFX  = 4 * T##SFX + q;                                          \
    const bool jv##SFX = (j##SFX < H) && (n < NB);                                \
    const int  jc##SFX = (j##SFX < H) ? j##SFX : 0;                               \
    short8 a1h##SFX[2], a1l##SFX[2], a2h##SFX[2], a2l##SFX[2],                    \
           a3h##SFX[2], a3l##SFX[2];                                              \
    loadA(whh1, T##SFX, n, q, a1h##SFX, a1l##SFX, 2);                             \
    loadA(whh2, T##SFX, n, q, a2h##SFX, a2l##SFX, 2);                             \
    loadA(wih2, T##SFX, n, q, a3h##SFX, a3l##SFX, 3);                             \
    const f32x4 b1v##SFX  = {bhh1[jc##SFX] + bih1[jc##SFX],                       \
                             bhh1[H + jc##SFX] + bih1[H + jc##SFX],               \
                             bhh1[2 * H + jc##SFX], bih1[2 * H + jc##SFX]};       \
    const f32x4 b2c2##SFX = {bhh2[jc##SFX] + bih2[jc##SFX],                       \
                             bhh2[H + jc##SFX] + bih2[H + jc##SFX],               \
                             bhh2[2 * H + jc##SFX], bih2[2 * H + jc##SFX]};       \
    const f32x4 ib2v##SFX = {bhh2[jc##SFX], bhh2[H + jc##SFX],                    \
                             bhh2[2 * H + jc##SFX], 0.f};                         \
    const f32x4 ic2v##SFX = {bih2[jc##SFX], bih2[H + jc##SFX], 0.f,               \
                             bih2[2 * H + jc##SFX]};                              \
    const float w1r##SFX = wih1[jc##SFX], w1z##SFX = wih1[H + jc##SFX],           \
                w1n##SFX = wih1[2 * H + jc##SFX];                                 \
    const float wl##SFX  = wlin[jc##SFX];                                         \
    float h1o##SFX = 0.f, h2o##SFX = 0.f;

    DECL_TILE(A, Ta)
    DECL_TILE(B, Tb)

    const float blin_r = blin[0];

    // ---- LDS init ----
    for (int i = t; i < 2 * 16 * KP; i += NT) { ((short*)sm.h1)[i] = 0; ((short*)sm.h2)[i] = 0; }
    for (int i = t; i < 2 * 16 * 4 * 8; i += NT) ((float*)sm.part)[i] = 0.f;
    if (t < 8) sm.olds[t] = 0.f;

    // ---- x staging: wave 6, lanes 0..7; parity-chunked double buffer ----
    const bool doX = (w == 6) && (lane < 8);
    const int  bs  = lane;
    const float* xrow = inp + (size_t)(bg * NB + (doX ? bs : 0)) * TSEQ;
    float4 xnxt = make_float4(0.f, 0.f, 0.f, 0.f);
    if (doX) {
        *(float4*)&sm.xstep[0][bs][0] = *(const float4*)xrow;     // x[0..3]
        xnxt = *(const float4*)(xrow + 4);                        // x[4..7]
    }

    const int TT = TSEQ + fut[0];
    float* outp = out + (size_t)(bg * NB) * (size_t)TT;
    __syncthreads();

// L2 step for one tile (main loop: combined whh2+wih2 8-MFMA chain, proven r4)
#define L2M(SFX, WPAR, PPAR)                                                      \
{                                                                                 \
    f32x4 g = dot4(a2h##SFX, a2l##SFX, b20, b21, b2c2##SFX);                      \
    g = dot4(a3h##SFX, a3l##SFX, b10, b11, g);                                    \
    const float gr = sigm(g.x);                                                   \
    const float gz = sigm(g.y);                                                   \
    const float gn = tanh_(fmaf(gr, g.z, g.w));                                   \
    const float hn = gn + gz * (h2o##SFX - gn);                                   \
    h2o##SFX = hn;                                                                \
    if (jv##SFX) { sm.h2[WPAR][n][j##SFX] = f2bf_rn(hn);                          \
                   sm.part[PPAR][T##SFX][q][n] = wl##SFX * hn; }                  \
}

// L1 step for one tile
#define L1M(SFX, WPAR, XV)                                                        \
{                                                                                 \
    const f32x4 a = dot4(a1h##SFX, a1l##SFX, b10, b11, b1v##SFX);                 \
    const float gr = sigm(fmaf((XV), w1r##SFX, a.x));                             \
    const float gz = sigm(fmaf((XV), w1z##SFX, a.y));                             \
    const float gn = tanh_(fmaf(gr, a.z, fmaf((XV), w1n##SFX, a.w)));             \
    const float hn = gn + gz * (h1o##SFX - gn);                                   \
    h1o##SFX = hn;                                                                \
    if (jv##SFX) sm.h1[WPAR][n][j##SFX] = f2bf_rn(hn);                            \
}

// wave-7 full output reduction: 13x4 tile-q partials per batch (pad tiles = 0)
#define RED14(PBUF, TIDX, SAVEO)                                                  \
{                                                                                 \
    const float* pb = &sm.part[PBUF][0][0][0];                                    \
    float v = 0.f;                                                                \
    _Pragma("unroll")                                                             \
    for (int c = 0; c < 8; ++c) v += pb[64 * c + lane];                           \
    v += __shfl_xor(v, 8);                                                        \
    v += __shfl_xor(v, 16);                                                       \
    v += __shfl_xor(v, 32);                                                       \
    if (lane < 8) {                                                               \
        const float o_ = v + blin_r;                                              \
        if (SAVEO) sm.olds[lane] = o_;                                            \
        outp[(size_t)lane * TT + (TIDX)] = o_;                                    \
    }                                                                             \
}

#define STEP(IV, PAR, DOL2, DORED)                                                \
{                                                                                 \
    const int i_ = (IV);                                                          \
    const short8 b10 = *(const short8*)&sm.h1[PAR][n][q * 8];                     \
    const short8 b11 = *(const short8*)&sm.h1[PAR][n][32 + q * 8];                \
    if (DOL2) {                                                                   \
        const short8 b20 = *(const short8*)&sm.h2[PAR][n][q * 8];                 \
        const short8 b21 = *(const short8*)&sm.h2[PAR][n][32 + q * 8];            \
        L2M(A, (PAR) ^ 1, PAR)                                                    \
        if (twoT) { L2M(B, (PAR) ^ 1, PAR) }                                      \
    }                                                                             \
    {                                                                             \
        const float xv = sm.xstep[(i_ >> 2) & 1][n & 7][i_ & 3];                  \
        L1M(A, (PAR) ^ 1, xv)                                                     \
        if (twoT) { L1M(B, (PAR) ^ 1, xv) }                                       \
    }                                                                             \
    if ((DORED) && w == 7) { RED14((PAR) ^ 1, i_ - 2, false) }                    \
    if (doX && (i_ & 3) == 3 && (i_ + 1) < TSEQ) {                                \
        *(float4*)&sm.xstep[((i_ + 1) >> 2) & 1][bs][0] = xnxt;                   \
        if (i_ + 8 < TSEQ) xnxt = *(const float4*)(xrow + i_ + 5);                \
    }                                                                             \
    BARR();                                                                       \
}

    // ========== MAIN LOOP: 1 barrier/step, parity-specialized unroll-2 ==========
    STEP(0, 0, false, false)
    STEP(1, 1, true,  false)
    for (int i = 2; i < TSEQ; i += 2) {
        STEP(i,     0, true, true)
        STEP(i + 1, 1, true, true)
    }

    // ========== EPILOGUE: h2(TSEQ-1), flush o(TSEQ-2) and o(TSEQ-1) ==========
    // state: h1(TSEQ-1) in h1[0], h2(TSEQ-2) in h2[0]; part[1] holds o(TSEQ-2) partials
    {
        const short8 b10 = *(const short8*)&sm.h1[0][n][q * 8];
        const short8 b11 = *(const short8*)&sm.h1[0][n][32 + q * 8];
        const short8 b20 = *(const short8*)&sm.h2[0][n][q * 8];
        const short8 b21 = *(const short8*)&sm.h2[0][n][32 + q * 8];
        L2M(A, 1, 0)
        if (twoT) { L2M(B, 1, 0) }
        if (w == 7) { RED14(1, TSEQ - 2, false) }
    }
    BARR();
    if (w == 7) { RED14(0, TSEQ - 1, true) }
    BARR();

    // ========== FUTURE LOOP: serial feedback, 3 barriers/step ==========
#define GSAVE(SFX)                                                                \
{   const f32x4 g = dot4(a2h##SFX, a2l##SFX, b20, b21, ib2v##SFX);                \
    g2r##SFX = g.x; g2z##SFX = g.y; g2n##SFX = g.z; }

#define L2F(SFX)                                                                  \
{                                                                                 \
    const f32x4 gi = dot4(a3h##SFX, a3l##SFX, c0, c1, ic2v##SFX);                 \
    const float gr = sigm(gi.x + g2r##SFX);                                       \
    const float gz = sigm(gi.y + g2z##SFX);                                       \
    const float gn = tanh_(fmaf(gr, g2n##SFX, gi.w));                             \
    const float hn = gn + gz * (h2o##SFX - gn);                                   \
    h2o##SFX = hn;                                                                \
    if (jv##SFX) { sm.h2[fh2 ^ 1][n][j##SFX] = f2bf_rn(hn);                       \
                   sm.part[0][T##SFX][q][n] = wl##SFX * hn; }                     \
}

    int fp1 = 0, fh2 = 1;    // h1(TSEQ-1) in h1[0], h2(TSEQ-1) in h2[1]
    for (int ts = TSEQ; ts < TT; ++ts) {
        float g2rA, g2zA, g2nA, g2rB, g2zB, g2nB;
        {
            const short8 b10 = *(const short8*)&sm.h1[fp1][n][q * 8];
            const short8 b11 = *(const short8*)&sm.h1[fp1][n][32 + q * 8];
            const short8 b20 = *(const short8*)&sm.h2[fh2][n][q * 8];
            const short8 b21 = *(const short8*)&sm.h2[fh2][n][32 + q * 8];
            const float  xv  = sm.olds[n & 7];
            GSAVE(A)
            L1M(A, fp1 ^ 1, xv)
            if (twoT) { GSAVE(B) L1M(B, fp1 ^ 1, xv) }
        }
        BARR();
        {
            const short8 c0 = *(const short8*)&sm.h1[fp1 ^ 1][n][q * 8];
            const short8 c1 = *(const short8*)&sm.h1[fp1 ^ 1][n][32 + q * 8];
            L2F(A)
            if (twoT) { L2F(B) }
        }
        BARR();
        if (w == 7) { RED14(0, ts, true) }
        BARR();
        fp1 ^= 1; fh2 ^= 1;
    }
}

extern "C" void kernel_launch(void* const* d_in, const int* in_sizes, int n_in,
                              void* d_out, int out_size, void* d_ws, size_t ws_size,
                              hipStream_t stream) {
    (void)in_sizes; (void)n_in; (void)d_ws; (void)ws_size; (void)out_size;
    gru_persist<<<BB / NB, NT, 0, stream>>>(
        (const float*)d_in[0], (const int*)d_in[1],
        (const float*)d_in[2], (const float*)d_in[3], (const float*)d_in[4], (const float*)d_in[5],
        (const float*)d_in[6], (const float*)d_in[7], (const float*)d_in[8], (const float*)d_in[9],
        (const float*)d_in[10], (const float*)d_in[11],
        (float*)d_out);
}

// Round 7
// 821.551 us; speedup vs baseline: 1.2146x; 1.1325x over previous
//
#include <hip/hip_runtime.h>

#define H    51
#define BB   2048
#define TSEQ 1024
#define NB   8
#define NT   1024       // 16 waves, 4/SIMD
#define KP   72         // f16 h-row stride (144B, 16B-aligned)

typedef __attribute__((ext_vector_type(8))) _Float16 half8;
typedef __attribute__((ext_vector_type(4))) float f32x4;

// v_rcp_f32 (1 ulp) via compiler-known intrinsic (proven r3)
__device__ __forceinline__ float rcp_(float x) { return __builtin_amdgcn_rcpf(x); }

__device__ __forceinline__ float sigm(float x) { return rcp_(1.0f + __expf(-x)); }
__device__ __forceinline__ float tanh_(float x) { return fmaf(-2.0f, rcp_(__expf(2.0f * x) + 1.0f), 1.0f); }

#define MFMA(a, b, c) __builtin_amdgcn_mfma_f32_16x16x32_f16((a), (b), (c), 0, 0, 0)

// lgkmcnt-only barrier (proven r3/r4): LDS ordering without draining vmcnt.
#define BARR() do { asm volatile("s_waitcnt lgkmcnt(0)" ::: "memory");            \
                    __builtin_amdgcn_s_barrier(); } while (0)

struct SM {
    alignas(16) _Float16 h1[2][16][KP];   // parity-buffered h1 (f16), [n][k]
    alignas(16) _Float16 h2[2][16][KP];   // parity-buffered h2
    alignas(16) float part[2][16][4][8];  // out partials [parity][tile(pad16)][q][batch]
    alignas(16) float xstep[2][8][4];     // parity-chunked x staging [buf][batch][slot]
    float olds[8];
};

// A-frags (single f16, no hi/lo split) for tile T of gate-stacked [3H][H]
// matrix, 4-padded rows: padded row 16T+n -> element j=4T+(n>>2), gate slot
// c=n&3. nslot selects which slot carries the n-gate row (2=normal; 3=moved).
// f16: 11 mantissa bits beats bf16-single; range safe (|w|<=0.15, |h|<1,
// accumulate in f32), so the 2x hi/lo MFMA duplication is unnecessary.
__device__ __forceinline__ void loadA(const float* __restrict__ src, int T, int n, int q,
                                      half8* a, int nslot) {
    const int jt = 4 * T + (n >> 2);
    const int c  = n & 3;
    const int g  = (c == 0) ? 0 : (c == 1) ? 1 : (c == nslot) ? 2 : -1;
    const bool rv = (g >= 0) && (jt < H);
#pragma unroll
    for (int kb = 0; kb < 2; ++kb) {
        half8 hv;
#pragma unroll
        for (int jj = 0; jj < 8; ++jj) {
            const int k = kb * 32 + q * 8 + jj;
            const float v = (rv && k < H) ? src[(g * H + jt) * H + k] : 0.f;
            hv[jj] = (_Float16)v;     // RNE
        }
        a[kb] = hv;
    }
}

// chained 2-MFMA matvec over K=64, bias/partial folded into accumulator init
__device__ __forceinline__ f32x4 dot2(const half8* a, half8 b0, half8 b1, f32x4 init) {
    f32x4 acc = init;
    acc = MFMA(a[0], b0, acc);
    acc = MFMA(a[1], b1, acc);
    return acc;
}

__global__ __launch_bounds__(NT, 1) void gru_persist(
    const float* __restrict__ inp, const int* __restrict__ fut,
    const float* __restrict__ wih1, const float* __restrict__ whh1,
    const float* __restrict__ bih1, const float* __restrict__ bhh1,
    const float* __restrict__ wih2, const float* __restrict__ whh2,
    const float* __restrict__ bih2, const float* __restrict__ bhh2,
    const float* __restrict__ wlin, const float* __restrict__ blin,
    float* __restrict__ out)
{
    __shared__ SM sm;
    const int t = threadIdx.x, bg = blockIdx.x;
    const int w = t >> 6, lane = t & 63;
    const int n = lane & 15, q = lane >> 4;
    // SIMD balance (proven r4): tile 12 on wave 15 -> light waves {12,13,14,15}
    // land on distinct SIMDs; every SIMD carries 3 matvec + 1 light wave.
    const bool doM = (w < 12) || (w == 15);
    const int  T   = (w == 15) ? 12 : (doM ? w : 0);
    const int  j   = 4 * T + q;
    const bool jv  = doM && (j < H) && (n < NB);
    const int  jcl = (j < H) ? j : 0;

    // ---- A-fragments: 6 half8 = 24 VGPRs (wih2's n-row in slot 3) ----
    half8 a1[2], a2[2], a3[2];
    loadA(whh1, T, n, q, a1, 2);
    loadA(whh2, T, n, q, a2, 2);
    loadA(wih2, T, n, q, a3, 3);

    // ---- per-lane constants; biases folded into f32x4 accumulator inits ----
    // L1 chain: .x/.y = both r/z biases, .z = bhh1n, .w = bih1n (zero slot-3 row)
    const f32x4 b1v  = {bhh1[jcl] + bih1[jcl], bhh1[H + jcl] + bih1[H + jcl],
                        bhh1[2 * H + jcl], bih1[2 * H + jcl]};
    // L2 combined chain (whh2 then wih2): same structure (proven r4)
    const f32x4 b2c2 = {bhh2[jcl] + bih2[jcl], bhh2[H + jcl] + bih2[H + jcl],
                        bhh2[2 * H + jcl], bih2[2 * H + jcl]};
    // future-loop split inits (phases separated by a barrier there)
    const f32x4 ib2v = {bhh2[jcl], bhh2[H + jcl], bhh2[2 * H + jcl], 0.f};
    const f32x4 ic2v = {bih2[jcl], bih2[H + jcl], 0.f, bih2[2 * H + jcl]};
    const float w1r = wih1[jcl], w1z = wih1[H + jcl], w1n = wih1[2 * H + jcl];
    const float wl  = wlin[jcl];
    const float blin_r = blin[0];

    // ---- LDS init ----
    for (int i = t; i < 2 * 16 * KP; i += NT) { ((short*)sm.h1)[i] = 0; ((short*)sm.h2)[i] = 0; }
    for (int i = t; i < 2 * 16 * 4 * 8; i += NT) ((float*)sm.part)[i] = 0.f;
    if (t < 8) sm.olds[t] = 0.f;

    // ---- x staging: wave 13, lanes 0..7; parity-chunked double buffer ----
    const bool doX = (w == 13) && (lane < 8);
    const int  bs  = lane;
    const float* xrow = inp + (size_t)(bg * NB + (doX ? bs : 0)) * TSEQ;
    float4 xnxt = make_float4(0.f, 0.f, 0.f, 0.f);
    if (doX) {
        *(float4*)&sm.xstep[0][bs][0] = *(const float4*)xrow;     // x[0..3]
        xnxt = *(const float4*)(xrow + 4);                        // x[4..7]
    }

    float h1o = 0.f, h2o = 0.f;     // per-lane f32 hidden (element j, batch n)
    const int TT = TSEQ + fut[0];
    float* outp = out + (size_t)(bg * NB) * (size_t)TT;
    __syncthreads();

// wave-14 full output reduction: 13x4 tile-q partials per batch; conflict-free
#define RED14(PBUF, TIDX, SAVEO)                                                  \
{                                                                                 \
    const float* pb = &sm.part[PBUF][0][0][0];                                    \
    float v = 0.f;                                                                \
    _Pragma("unroll")                                                             \
    for (int c = 0; c < 8; ++c) v += pb[64 * c + lane];                           \
    v += __shfl_xor(v, 8);                                                        \
    v += __shfl_xor(v, 16);                                                       \
    v += __shfl_xor(v, 32);                                                       \
    if (lane < 8) {                                                               \
        const float o_ = v + blin_r;                                              \
        if (SAVEO) sm.olds[lane] = o_;                                            \
        outp[(size_t)lane * TT + (TIDX)] = o_;                                    \
    }                                                                             \
}

#define STEP(IV, PAR, DOL2, DORED)                                                \
{                                                                                 \
    const int i_ = (IV);                                                          \
    if (doM) {                                                                    \
        const half8 b10 = *(const half8*)&sm.h1[PAR][n][q * 8];                   \
        const half8 b11 = *(const half8*)&sm.h1[PAR][n][32 + q * 8];              \
        if (DOL2) {                                                               \
            const half8 b20 = *(const half8*)&sm.h2[PAR][n][q * 8];               \
            const half8 b21 = *(const half8*)&sm.h2[PAR][n][32 + q * 8];          \
            f32x4 g = dot2(a2, b20, b21, b2c2);                                   \
            g = dot2(a3, b10, b11, g);                                            \
            const float gr = sigm(g.x);                                           \
            const float gz = sigm(g.y);                                           \
            const float gn = tanh_(fmaf(gr, g.z, g.w));                           \
            const float hn = gn + gz * (h2o - gn);                                \
            h2o = hn;                                                             \
            if (jv) { sm.h2[(PAR) ^ 1][n][j] = (_Float16)hn;                      \
                      sm.part[PAR][T][q][n] = wl * hn; }                          \
        }                                                                         \
        {                                                                         \
            const float xv = sm.xstep[(i_ >> 2) & 1][n & 7][i_ & 3];              \
            const f32x4 a = dot2(a1, b10, b11, b1v);                              \
            const float gr = sigm(fmaf(xv, w1r, a.x));                            \
            const float gz = sigm(fmaf(xv, w1z, a.y));                            \
            const float gn = tanh_(fmaf(gr, a.z, fmaf(xv, w1n, a.w)));            \
            const float hn = gn + gz * (h1o - gn);                                \
            h1o = hn;                                                             \
            if (jv) sm.h1[(PAR) ^ 1][n][j] = (_Float16)hn;                        \
        }                                                                         \
    } else if (w == 14) {                                                         \
        if (DORED) RED14((PAR) ^ 1, i_ - 2, false)                                \
    } else if (doX && (i_ & 3) == 3 && (i_ + 1) < TSEQ) {                         \
        *(float4*)&sm.xstep[((i_ + 1) >> 2) & 1][bs][0] = xnxt;                   \
        if (i_ + 8 < TSEQ) xnxt = *(const float4*)(xrow + i_ + 5);                \
    }                                                                             \
    BARR();                                                                       \
}

    // ========== MAIN LOOP: 1 barrier/step, parity-specialized unroll-2 ==========
    STEP(0, 0, false, false)
    STEP(1, 1, true,  false)
    for (int i = 2; i < TSEQ; i += 2) {
        STEP(i,     0, true, true)
        STEP(i + 1, 1, true, true)
    }

    // ========== EPILOGUE: h2(TSEQ-1), flush o(TSEQ-2) and o(TSEQ-1) ==========
    // state: h1(TSEQ-1) in h1[0], h2(TSEQ-2) in h2[0]; part[1] holds o(TSEQ-2) partials
    if (doM) {
        const half8 b10 = *(const half8*)&sm.h1[0][n][q * 8];
        const half8 b11 = *(const half8*)&sm.h1[0][n][32 + q * 8];
        const half8 b20 = *(const half8*)&sm.h2[0][n][q * 8];
        const half8 b21 = *(const half8*)&sm.h2[0][n][32 + q * 8];
        f32x4 g = dot2(a2, b20, b21, b2c2);
        g = dot2(a3, b10, b11, g);
        const float gr = sigm(g.x);
        const float gz = sigm(g.y);
        const float gn = tanh_(fmaf(gr, g.z, g.w));
        const float hn = gn + gz * (h2o - gn);
        h2o = hn;
        if (jv) { sm.h2[1][n][j] = (_Float16)hn; sm.part[0][T][q][n] = wl * hn; }
    } else if (w == 14) {
        RED14(1, TSEQ - 2, false)
    }
    BARR();
    if (w == 14) {
        RED14(0, TSEQ - 1, true)
    }
    BARR();

    // ========== FUTURE LOOP: serial feedback, 3 barriers/step ==========
    int fp1 = 0, fh2 = 1;    // h1(TSEQ-1) in h1[0], h2(TSEQ-1) in h2[1]
    for (int ts = TSEQ; ts < TT; ++ts) {
        float g2r, g2z, g2n;
        if (doM) {
            const half8 b10 = *(const half8*)&sm.h1[fp1][n][q * 8];
            const half8 b11 = *(const half8*)&sm.h1[fp1][n][32 + q * 8];
            const half8 b20 = *(const half8*)&sm.h2[fh2][n][q * 8];
            const half8 b21 = *(const half8*)&sm.h2[fh2][n][32 + q * 8];
            const float  xv  = sm.olds[n & 7];
            {
                const f32x4 g = dot2(a2, b20, b21, ib2v);
                g2r = g.x; g2z = g.y; g2n = g.z;
            }
            {
                const f32x4 a = dot2(a1, b10, b11, b1v);
                const float gr = sigm(fmaf(xv, w1r, a.x));
                const float gz = sigm(fmaf(xv, w1z, a.y));
                const float gn = tanh_(fmaf(gr, a.z, fmaf(xv, w1n, a.w)));
                const float hn = gn + gz * (h1o - gn);
                h1o = hn;
                if (jv) sm.h1[fp1 ^ 1][n][j] = (_Float16)hn;
            }
        }
        BARR();
        if (doM) {
            const half8 c0 = *(const half8*)&sm.h1[fp1 ^ 1][n][q * 8];
            const half8 c1 = *(const half8*)&sm.h1[fp1 ^ 1][n][32 + q * 8];
            const f32x4 gi = dot2(a3, c0, c1, ic2v);         // n-part lands in .w
            const float gr = sigm(gi.x + g2r);
            const float gz = sigm(gi.y + g2z);
            const float gn = tanh_(fmaf(gr, g2n, gi.w));
            const float hn = gn + gz * (h2o - gn);
            h2o = hn;
            if (jv) { sm.h2[fh2 ^ 1][n][j] = (_Float16)hn; sm.part[0][T][q][n] = wl * hn; }
        }
        BARR();
        if (w == 14) {
            RED14(0, ts, true)
        }
        BARR();
        fp1 ^= 1; fh2 ^= 1;
    }
}

extern "C" void kernel_launch(void* const* d_in, const int* in_sizes, int n_in,
                              void* d_out, int out_size, void* d_ws, size_t ws_size,
                              hipStream_t stream) {
    (void)in_sizes; (void)n_in; (void)d_ws; (void)ws_size; (void)out_size;
    gru_persist<<<BB / NB, NT, 0, stream>>>(
        (const float*)d_in[0], (const int*)d_in[1],
        (const float*)d_in[2], (const float*)d_in[3], (const float*)d_in[4], (const float*)d_in[5],
        (const float*)d_in[6], (const float*)d_in[7], (const float*)d_in[8], (const float*)d_in[9],
        (const float*)d_in[10], (const float*)d_in[11],
        (float*)d_out);
}

// Round 8
// 765.172 us; speedup vs baseline: 1.3041x; 1.0737x over previous
//
#include <hip/hip_runtime.h>

#define H    51
#define BB   2048
#define TSEQ 1024
#define NB   8
#define NT   1024       // 16 waves, 4/SIMD
#define KP   72         // f16 h-row stride (144B, 16B-aligned)
#define XSL  51         // x (layer-1 input) lives in k-slot 51 of the h1 buffer

typedef __attribute__((ext_vector_type(8))) _Float16 half8;
typedef __attribute__((ext_vector_type(4))) float f32x4;

// v_rcp_f32 (1 ulp) via compiler-known intrinsic (proven r3)
__device__ __forceinline__ float rcp_(float x) { return __builtin_amdgcn_rcpf(x); }

__device__ __forceinline__ float sigm(float x) { return rcp_(1.0f + __expf(-x)); }
__device__ __forceinline__ float tanh_(float x) { return fmaf(-2.0f, rcp_(__expf(2.0f * x) + 1.0f), 1.0f); }

#define MFMA(a, b, c) __builtin_amdgcn_mfma_f32_16x16x32_f16((a), (b), (c), 0, 0, 0)

// lgkmcnt-only barrier (proven r3/r4): LDS ordering without draining vmcnt.
#define BARR() do { asm volatile("s_waitcnt lgkmcnt(0)" ::: "memory");            \
                    __builtin_amdgcn_s_barrier(); } while (0)

struct SM {
    alignas(16) _Float16 h1[2][16][KP];   // parity-buffered h1 (f16); k=51 carries x
    alignas(16) _Float16 h2[2][16][KP];   // parity-buffered h2 (k>=51 stays 0)
};

// A-frags (f16) for tile T of gate-stacked [3H][H] matrix, 4-padded rows:
// padded row 16T+n -> element j=4T+(n>>2), gate slot c=n&3.
// nslot selects which slot carries the n-gate row (2 = normal; 3 = moved).
__device__ __forceinline__ void loadA(const float* __restrict__ src, int T, int n, int q,
                                      half8* a, int nslot) {
    const int jt = 4 * T + (n >> 2);
    const int c  = n & 3;
    const int g  = (c == 0) ? 0 : (c == 1) ? 1 : (c == nslot) ? 2 : -1;
    const bool rv = (g >= 0) && (jt < H);
#pragma unroll
    for (int kb = 0; kb < 2; ++kb) {
        half8 hv;
#pragma unroll
        for (int jj = 0; jj < 8; ++jj) {
            const int k = kb * 32 + q * 8 + jj;
            const float v = (rv && k < H) ? src[(g * H + jt) * H + k] : 0.f;
            hv[jj] = (_Float16)v;     // RNE
        }
        a[kb] = hv;
    }
}

// L1 A-frag: whh1 rows for k<51 PLUS wih1 column at k==XSL (x rides the MFMA):
// slot c0: [whh1_r | w1r@51], c1: [whh1_z | w1z@51], c2: [whh1_n | 0@51],
// c3: [0 | w1n@51]  ->  a.w accumulates bih1n + w1n*x (i-side of n gate).
__device__ __forceinline__ void loadA1(const float* __restrict__ whh1,
                                       const float* __restrict__ wih1,
                                       int T, int n, int q, half8* a) {
    const int jt = 4 * T + (n >> 2);
    const int c  = n & 3;
    const bool jok = (jt < H);
#pragma unroll
    for (int kb = 0; kb < 2; ++kb) {
        half8 hv;
#pragma unroll
        for (int jj = 0; jj < 8; ++jj) {
            const int k = kb * 32 + q * 8 + jj;
            float v = 0.f;
            if (jok) {
                if (c < 2) {
                    if (k < H)        v = whh1[(c * H + jt) * H + k];
                    else if (k == XSL) v = wih1[c * H + jt];
                } else if (c == 2) {
                    if (k < H)        v = whh1[(2 * H + jt) * H + k];
                } else {              // c == 3: x-only row for the n gate
                    if (k == XSL)     v = wih1[2 * H + jt];
                }
            }
            hv[jj] = (_Float16)v;
        }
        a[kb] = hv;
    }
}

// chained 2-MFMA matvec over K=64, bias/partial folded into accumulator init
__device__ __forceinline__ f32x4 dot2(const half8* a, half8 b0, half8 b1, f32x4 init) {
    f32x4 acc = init;
    acc = MFMA(a[0], b0, acc);
    acc = MFMA(a[1], b1, acc);
    return acc;
}

__global__ __launch_bounds__(NT, 1) void gru_persist(
    const float* __restrict__ inp, const int* __restrict__ fut,
    const float* __restrict__ wih1, const float* __restrict__ whh1,
    const float* __restrict__ bih1, const float* __restrict__ bhh1,
    const float* __restrict__ wih2, const float* __restrict__ whh2,
    const float* __restrict__ bih2, const float* __restrict__ bhh2,
    const float* __restrict__ wlin, const float* __restrict__ blin,
    float* __restrict__ out)
{
    __shared__ SM sm;
    const int t = threadIdx.x, bg = blockIdx.x;
    const int w = t >> 6, lane = t & 63;
    const int n = lane & 15, q = lane >> 4;
    // SIMD balance (proven r4): tile 12 on wave 15 -> light waves {12,13,14,15}
    // land on distinct SIMDs; every SIMD carries 3 matvec + 1 light wave.
    const bool doM = (w < 12) || (w == 15);
    const int  T   = (w == 15) ? 12 : (doM ? w : 0);
    const int  j   = 4 * T + q;
    const bool jv  = doM && (j < H) && (n < NB);
    const int  jcl = (j < H) ? j : 0;

    // ---- A-fragments: 6 half8 = 24 VGPRs (wih2's n-row in slot 3) ----
    half8 a1[2], a2[2], a3[2];
    loadA1(whh1, wih1, T, n, q, a1);
    loadA(whh2, T, n, q, a2, 2);
    loadA(wih2, T, n, q, a3, 3);

    // ---- per-lane constants; biases folded into f32x4 accumulator inits ----
    // L1: .x/.y = both r/z biases, .z = bhh1n, .w = bih1n (x-term lands via MFMA)
    const f32x4 b1v  = {bhh1[jcl] + bih1[jcl], bhh1[H + jcl] + bih1[H + jcl],
                        bhh1[2 * H + jcl], bih1[2 * H + jcl]};
    // L2 combined chain (whh2 then wih2): proven r4
    const f32x4 b2c2 = {bhh2[jcl] + bih2[jcl], bhh2[H + jcl] + bih2[H + jcl],
                        bhh2[2 * H + jcl], bih2[2 * H + jcl]};
    // future-loop split inits (phases separated by a barrier there)
    const f32x4 ib2v = {bhh2[jcl], bhh2[H + jcl], bhh2[2 * H + jcl], 0.f};
    const f32x4 ic2v = {bih2[jcl], bih2[H + jcl], 0.f, bih2[2 * H + jcl]};
    const float blin_r = blin[0];

    // ---- reducer constants (wave 14): lane = n8*8+c8 covers batch x k-chunk ----
    const int n8 = lane >> 3, c8 = lane & 7;
    float wlv[8];
#pragma unroll
    for (int jj = 0; jj < 8; ++jj) {
        const int ix = c8 * 8 + jj;
        wlv[jj] = (ix < H) ? wlin[ix] : 0.f;
    }

    // ---- LDS init (zeros; x/o slots written after the fence) ----
    for (int i = t; i < 2 * 16 * KP; i += NT) { ((short*)sm.h1)[i] = 0; ((short*)sm.h2)[i] = 0; }
    __syncthreads();

    // ---- x staging: wave 13, lanes 0..7 write x(i+1) -> h1[PAR^1][bs][XSL] ----
    const bool doX = (w == 13) && (lane < 8);
    const int  bs  = lane;
    const float* xrow = inp + (size_t)(bg * NB + (doX ? bs : 0)) * TSEQ;
    float4 cn = make_float4(0.f, 0.f, 0.f, 0.f);
    float4 nx = make_float4(0.f, 0.f, 0.f, 0.f);
    if (doX) {
        cn = *(const float4*)xrow;                 // x[0..3]
        nx = *(const float4*)(xrow + 4);           // x[4..7]
        sm.h1[0][bs][XSL] = (_Float16)cn.x;        // x(0)
    }

    float h1o = 0.f, h2o = 0.f;     // per-lane f32 hidden (element j, batch n)
    const int TT = TSEQ + fut[0];
    float* outp = out + (size_t)(bg * NB) * (size_t)TT;
    __syncthreads();

// reducer: o = wlin . h2[PARI] + b via ONE ds_read_b128 (replaces part[] traffic)
#define REDH(PARI, TIDX, DOWR, WRP)                                               \
{                                                                                 \
    const half8 hv = *(const half8*)&sm.h2[PARI][n8][c8 * 8];                     \
    float v = 0.f;                                                                \
    _Pragma("unroll")                                                             \
    for (int jj = 0; jj < 8; ++jj) v = fmaf((float)hv[jj], wlv[jj], v);           \
    v += __shfl_xor(v, 1);                                                        \
    v += __shfl_xor(v, 2);                                                        \
    v += __shfl_xor(v, 4);                                                        \
    if (c8 == 0) {                                                                \
        const float o_ = v + blin_r;                                              \
        if (DOWR) sm.h1[WRP][n8][XSL] = (_Float16)o_;                             \
        outp[(size_t)n8 * TT + (TIDX)] = o_;                                      \
    }                                                                             \
}

// XC = (IV+1)&3, a compile-time literal per unrolled position (rule #20)
#define STEP(IV, PAR, XC, DOL2, DORED)                                            \
{                                                                                 \
    const int i_ = (IV);                                                          \
    if (doM) {                                                                    \
        const half8 b10 = *(const half8*)&sm.h1[PAR][n][q * 8];                   \
        const half8 b11 = *(const half8*)&sm.h1[PAR][n][32 + q * 8];              \
        if (DOL2) {                                                               \
            const half8 b20 = *(const half8*)&sm.h2[PAR][n][q * 8];               \
            const half8 b21 = *(const half8*)&sm.h2[PAR][n][32 + q * 8];          \
            f32x4 g = dot2(a2, b20, b21, b2c2);                                   \
            g = dot2(a3, b10, b11, g);                                            \
            const float gr = sigm(g.x);                                           \
            const float gz = sigm(g.y);                                           \
            const float gn = tanh_(fmaf(gr, g.z, g.w));                           \
            const float hn = gn + gz * (h2o - gn);                                \
            h2o = hn;                                                             \
            if (jv) sm.h2[(PAR) ^ 1][n][j] = (_Float16)hn;                        \
        }                                                                         \
        {                                                                         \
            const f32x4 a = dot2(a1, b10, b11, b1v);   /* x-term via k=51 */      \
            const float gr = sigm(a.x);                                           \
            const float gz = sigm(a.y);                                           \
            const float gn = tanh_(fmaf(gr, a.z, a.w));                           \
            const float hn = gn + gz * (h1o - gn);                                \
            h1o = hn;                                                             \
            if (jv) sm.h1[(PAR) ^ 1][n][j] = (_Float16)hn;                        \
        }                                                                         \
    } else if (w == 14) {                                                         \
        if (DORED) REDH(PAR, i_ - 2, false, 0)                                    \
    } else if (doX && (i_ + 1) < TSEQ) {                                          \
        if ((XC) == 0) cn = nx;                                                   \
        const float xv_ = ((XC) == 0) ? cn.x : ((XC) == 1) ? cn.y                 \
                        : ((XC) == 2) ? cn.z : cn.w;                              \
        sm.h1[(PAR) ^ 1][bs][XSL] = (_Float16)xv_;                                \
        if ((XC) == 0 && (i_ + 5) < TSEQ) nx = *(const float4*)(xrow + i_ + 5);   \
    }                                                                             \
    BARR();                                                                       \
}

    // ========== MAIN LOOP: 1 barrier/step, unroll-4 (static x-component) ==========
    STEP(0, 0, 1, false, false)
    STEP(1, 1, 2, true,  false)
    for (int i = 2; i < TSEQ - 2; i += 4) {
        STEP(i,     0, 3, true, true)
        STEP(i + 1, 1, 0, true, true)
        STEP(i + 2, 0, 1, true, true)
        STEP(i + 3, 1, 2, true, true)
    }
    STEP(TSEQ - 2, 0, 3, true, true)
    STEP(TSEQ - 1, 1, 0, true, true)

    // ========== EPILOGUE: h2(TSEQ-1), flush o(TSEQ-2) and o(TSEQ-1) ==========
    // state: h1(TSEQ-1) in h1[0], h2(TSEQ-2) in h2[0]
    if (doM) {
        const half8 b10 = *(const half8*)&sm.h1[0][n][q * 8];
        const half8 b11 = *(const half8*)&sm.h1[0][n][32 + q * 8];
        const half8 b20 = *(const half8*)&sm.h2[0][n][q * 8];
        const half8 b21 = *(const half8*)&sm.h2[0][n][32 + q * 8];
        f32x4 g = dot2(a2, b20, b21, b2c2);
        g = dot2(a3, b10, b11, g);
        const float gr = sigm(g.x);
        const float gz = sigm(g.y);
        const float gn = tanh_(fmaf(gr, g.z, g.w));
        const float hn = gn + gz * (h2o - gn);
        h2o = hn;
        if (jv) sm.h2[1][n][j] = (_Float16)hn;
    } else if (w == 14) {
        REDH(0, TSEQ - 2, false, 0)
    }
    BARR();
    if (w == 14) {
        REDH(1, TSEQ - 1, true, 0)      // o(TSEQ-1) -> out + h1[0] x-slot (future x)
    }
    BARR();

    // ========== FUTURE LOOP: serial feedback, 3 barriers/step ==========
    // L1 is IDENTICAL to the main loop (x = o rides slot 51 of h1).
    int fp1 = 0, fh2 = 1;    // h1(TSEQ-1)+o in h1[0], h2(TSEQ-1) in h2[1]
    for (int ts = TSEQ; ts < TT; ++ts) {
        float g2r, g2z, g2n;
        if (doM) {
            const half8 b10 = *(const half8*)&sm.h1[fp1][n][q * 8];
            const half8 b11 = *(const half8*)&sm.h1[fp1][n][32 + q * 8];
            const half8 b20 = *(const half8*)&sm.h2[fh2][n][q * 8];
            const half8 b21 = *(const half8*)&sm.h2[fh2][n][32 + q * 8];
            {
                const f32x4 g = dot2(a2, b20, b21, ib2v);
                g2r = g.x; g2z = g.y; g2n = g.z;
            }
            {
                const f32x4 a = dot2(a1, b10, b11, b1v);   // x-term via k=51
                const float gr = sigm(a.x);
                const float gz = sigm(a.y);
                const float gn = tanh_(fmaf(gr, a.z, a.w));
                const float hn = gn + gz * (h1o - gn);
                h1o = hn;
                if (jv) sm.h1[fp1 ^ 1][n][j] = (_Float16)hn;
            }
        }
        BARR();
        if (doM) {
            const half8 c0 = *(const half8*)&sm.h1[fp1 ^ 1][n][q * 8];
            const half8 c1 = *(const half8*)&sm.h1[fp1 ^ 1][n][32 + q * 8];
            const f32x4 gi = dot2(a3, c0, c1, ic2v);       // n-part lands in .w
            const float gr = sigm(gi.x + g2r);
            const float gz = sigm(gi.y + g2z);
            const float gn = tanh_(fmaf(gr, g2n, gi.w));
            const float hn = gn + gz * (h2o - gn);
            h2o = hn;
            if (jv) sm.h2[fh2 ^ 1][n][j] = (_Float16)hn;
        }
        BARR();
        if (w == 14) {
            REDH(fh2 ^ 1, ts, true, fp1 ^ 1)   // o(ts) -> out + next step's x-slot
        }
        BARR();
        fp1 ^= 1; fh2 ^= 1;
    }
}

extern "C" void kernel_launch(void* const* d_in, const int* in_sizes, int n_in,
                              void* d_out, int out_size, void* d_ws, size_t ws_size,
                              hipStream_t stream) {
    (void)in_sizes; (void)n_in; (void)d_ws; (void)ws_size; (void)out_size;
    gru_persist<<<BB / NB, NT, 0, stream>>>(
        (const float*)d_in[0], (const int*)d_in[1],
        (const float*)d_in[2], (const float*)d_in[3], (const float*)d_in[4], (const float*)d_in[5],
        (const float*)d_in[6], (const float*)d_in[7], (const float*)d_in[8], (const float*)d_in[9],
        (const float*)d_in[10], (const float*)d_in[11],
        (float*)d_out);
}